// Round 2
// baseline (449.554 us; speedup 1.0000x reference)
//
#include <hip/hip_runtime.h>
#include <math.h>

#define ROWS 16384
#define DD   4096
#define EE   64
#define EPSF 1e-10f

#define BM    64                 // rows per gemm block
#define KT    32                 // k per tile
#define NKT   (DD / KT)          // 128 k-tiles, full K per block (KSPLIT=1)
#define WTILE 12288              // bytes per pre-split w k-tile (3*4*64*16)

typedef __attribute__((ext_vector_type(8))) short short8;   // 8 bf16
typedef __attribute__((ext_vector_type(4))) float f32x4;    // MFMA C/D
typedef __attribute__((ext_vector_type(4))) unsigned u32x4; // packed bf16x8

// RNE 3-level bf16 split of 8 floats, pair-packed into 3x (4 dwords).
__device__ __forceinline__ void split3x8(const float f[8], u32x4& w0,
                                         u32x4& w1, u32x4& w2) {
#pragma unroll
  for (int i = 0; i < 4; ++i) {
    float fa = f[2 * i], fb = f[2 * i + 1];
    unsigned ua = __float_as_uint(fa), ub = __float_as_uint(fb);
    unsigned ra = ua + 0x7fffu + ((ua >> 16) & 1u);
    unsigned rb = ub + 0x7fffu + ((ub >> 16) & 1u);
    w0[i] = (rb & 0xffff0000u) | (ra >> 16);
    fa -= __uint_as_float(ra & 0xffff0000u);
    fb -= __uint_as_float(rb & 0xffff0000u);
    ua = __float_as_uint(fa); ub = __float_as_uint(fb);
    ra = ua + 0x7fffu + ((ua >> 16) & 1u);
    rb = ub + 0x7fffu + ((ub >> 16) & 1u);
    w1[i] = (rb & 0xffff0000u) | (ra >> 16);
    fa -= __uint_as_float(ra & 0xffff0000u);
    fb -= __uint_as_float(rb & 0xffff0000u);
    ua = __float_as_uint(fa); ub = __float_as_uint(fb);
    ra = ua + 0x7fffu + ((ua >> 16) & 1u);
    rb = ub + 0x7fffu + ((ub >> 16) & 1u);
    w2[i] = (rb & 0xffff0000u) | (ra >> 16);
  }
}

__device__ __forceinline__ void dma16(const void* g, void* l) {
  __builtin_amdgcn_global_load_lds(
      (const __attribute__((address_space(1))) unsigned int*)g,
      (__attribute__((address_space(3))) unsigned int*)l, 16, 0, 0);
}

// ---------------------------------------------------------------------------
// One-time w pre-split into MFMA-B-fragment-ready layout:
//   wsp[kt][part p][et][lp][8 bf16]; lp = k_octet*16 + (e&15), et = e>>4.
// Block 0 also zeroes g_load (stream-ordered before k_gemm's atomics).
// ---------------------------------------------------------------------------
__global__ __launch_bounds__(256) void k_wsplit(const float* __restrict__ wr,
                                                unsigned char* __restrict__ out,
                                                float* __restrict__ g_load) {
  const int kt = blockIdx.x;  // global k-tile 0..127
  const int t = threadIdx.x;
  const int lane = t & 63, wv = t >> 6;
  if (blockIdx.x == 0 && t < 64) g_load[t] = 0.f;
  float f[8];
  const float* wp = wr + (size_t)(kt * 32 + wv * 8) * EE + lane;
#pragma unroll
  for (int j = 0; j < 8; ++j) f[j] = wp[(size_t)j * EE];
  u32x4 w0, w1, w2;
  split3x8(f, w0, w1, w2);
  const int et = lane >> 4;
  const int lp = wv * 16 + (lane & 15);
  unsigned char* base = out + (size_t)kt * WTILE + et * 1024 + lp * 16;
  *(u32x4*)(base + 0 * 4096) = w0;
  *(u32x4*)(base + 1 * 4096) = w1;
  *(u32x4*)(base + 2 * 4096) = w2;
}

// ---------------------------------------------------------------------------
// Router GEMM + fused softmax/expert-load.
// 256 blocks x 512 thr (8 waves): 64 rows x 64 experts x FULL K=4096.
// Wave wv: m-tile mt=wv>>1 (16 rows), e-half eh=wv&1 (2 of 4 e-tiles).
// A: per-lane global float4 loads (h reuse=1, no staging).
// B: pre-split frags DMA'd global->LDS (global_load_lds, double-buffered).
// One barrier per kt; prefetch issued right after the barrier.
// Epilogue: raw logits -> LDS -> per-row softmax -> g_load atomics (1/blk/exp)
// and direct coalesced logits stores. No KSPLIT, no logits atomics, no memset.
// ---------------------------------------------------------------------------
__global__ __launch_bounds__(512) void k_gemm(
    const float* __restrict__ h, const unsigned char* __restrict__ wsp,
    float* __restrict__ logits, float* __restrict__ g_load) {
  __shared__ alignas(16) unsigned char smem[2 * WTILE];  // 24 KB

  const int t = threadIdx.x;
  const int lane = t & 63;
  const int wv = t >> 6;    // 0..7
  const int mt = wv >> 1;   // m-tile 0..3
  const int eh = wv & 1;    // e-half 0..1
  const int row0 = blockIdx.x * BM;

  f32x4 acc[2] = {};

  // A: row = row0 + mt*16 + (lane&15), k = (lane>>4)*8 + j
  const float* ap =
      h + (size_t)(row0 + mt * 16 + (lane & 15)) * DD + (lane >> 4) * 8;

  const int slot0 = wv * 1024 + lane * 16;  // dma byte offset (wave-uniform base)

  float4 cur0, cur1, nxt0, nxt1;
  cur0 = *(const float4*)(ap);
  cur1 = *(const float4*)(ap + 4);
  dma16(wsp + slot0, smem + slot0);
  if (wv < 4) dma16(wsp + 8192 + slot0, smem + 8192 + slot0);

  for (int kt = 0; kt < NKT; ++kt) {
    const int buf = kt & 1;
    const unsigned char* lb = smem + buf * WTILE;
    asm volatile("s_waitcnt vmcnt(0)" ::: "memory");
    __syncthreads();

    // issue next-tile prefetch NOW; full compute phase to land
    if (kt + 1 < NKT) {
      const float* p = ap + (size_t)(kt + 1) * KT;
      nxt0 = *(const float4*)(p);
      nxt1 = *(const float4*)(p + 4);
      const unsigned char* ws = wsp + (size_t)(kt + 1) * WTILE;
      unsigned char* nb = smem + (buf ^ 1) * WTILE;
      dma16(ws + slot0, nb + slot0);
      if (wv < 4) dma16(ws + 8192 + slot0, nb + 8192 + slot0);
    }

    // B fragments: 3 parts x 2 e-tiles, 16B/lane linear (2-way bank = free)
    short8 bf[3][2];
#pragma unroll
    for (int p = 0; p < 3; ++p)
#pragma unroll
      for (int e = 0; e < 2; ++e)
        bf[p][e] = *(const short8*)&lb[p * 4096 + (eh * 2 + e) * 1024 +
                                       lane * 16];

    const float af[8] = {cur0.x, cur0.y, cur0.z, cur0.w,
                         cur1.x, cur1.y, cur1.z, cur1.w};
    u32x4 q0, q1, q2;
    split3x8(af, q0, q1, q2);
    const short8 ah0 = __builtin_bit_cast(short8, q0);
    const short8 ah1 = __builtin_bit_cast(short8, q1);
    const short8 ah2 = __builtin_bit_cast(short8, q2);
#pragma unroll
    for (int e = 0; e < 2; ++e) {
      f32x4 c = acc[e];
      c = __builtin_amdgcn_mfma_f32_16x16x32_bf16(ah0, bf[0][e], c, 0, 0, 0);
      c = __builtin_amdgcn_mfma_f32_16x16x32_bf16(ah0, bf[1][e], c, 0, 0, 0);
      c = __builtin_amdgcn_mfma_f32_16x16x32_bf16(ah1, bf[0][e], c, 0, 0, 0);
      c = __builtin_amdgcn_mfma_f32_16x16x32_bf16(ah0, bf[2][e], c, 0, 0, 0);
      c = __builtin_amdgcn_mfma_f32_16x16x32_bf16(ah1, bf[1][e], c, 0, 0, 0);
      c = __builtin_amdgcn_mfma_f32_16x16x32_bf16(ah2, bf[0][e], c, 0, 0, 0);
      acc[e] = c;
    }

    if (kt + 1 < NKT) { cur0 = nxt0; cur1 = nxt1; }
  }

  // ---- fused epilogue: raw logits -> LDS -> softmax -> load accumulation ----
  __syncthreads();                       // all waves done reading smem
  float* sl = (float*)smem;              // [64][68] fp32, padded stride
  {
    const int rb = mt * 16 + (lane >> 4) * 4;     // C: row=quad*4+r
    const int cb = eh * 32 + (lane & 15);         //    col=lane&15
#pragma unroll
    for (int e = 0; e < 2; ++e)
#pragma unroll
      for (int r = 0; r < 4; ++r)
        sl[(rb + r) * 68 + cb + e * 16] = acc[e][r];
  }
  __syncthreads();

  float accp = 0.f;
#pragma unroll
  for (int i = 0; i < 8; ++i) {
    const int row = wv * 8 + i;
    const float x = sl[row * 68 + lane];
    float m = x;
#pragma unroll
    for (int off = 32; off > 0; off >>= 1) m = fmaxf(m, __shfl_xor(m, off, 64));
    const float p = __expf(x - m);
    float s = p;
#pragma unroll
    for (int off = 32; off > 0; off >>= 1) s += __shfl_xor(s, off, 64);
    accp += p / s;
    logits[(size_t)(row0 + row) * EE + lane] = x;   // raw logits, coalesced
  }
  float* red = sl + 64 * 68;             // disjoint LDS region
  red[wv * 64 + lane] = accp;
  __syncthreads();
  if (wv == 0) {
    float s = 0.f;
#pragma unroll
    for (int j = 0; j < 8; ++j) s += red[j * 64 + lane];
    atomicAdd(&g_load[lane], s);
  }
}

// ---------------------------------------------------------------------------
// penalty (recomputed per wave: 64-wide reduce + logf, trivially cheap)
// + adjusted logits + top-2. One row per wave.
// ---------------------------------------------------------------------------
__global__ __launch_bounds__(256) void k_top2(float* __restrict__ logits,
                                              const float* __restrict__ g_load,
                                              float* __restrict__ idx_out) {
  int t = threadIdx.x;
  int lane = t & 63;
  int wv = t >> 6;
  int row = blockIdx.x * 4 + wv;

  float v0 = g_load[lane];
  float s0 = v0;
#pragma unroll
  for (int off = 32; off > 0; off >>= 1) s0 += __shfl_xor(s0, off, 64);
  float lp = logf(v0 / (s0 * (1.f / 64.f) + EPSF) + EPSF);

  size_t base = (size_t)row * EE;
  float a = logits[base + lane] - lp;
  logits[base + lane] = a;

  float v = a;
  int idx = lane;
#pragma unroll
  for (int off = 32; off > 0; off >>= 1) {
    float ov = __shfl_xor(v, off, 64);
    int oi = __shfl_xor(idx, off, 64);
    if (ov > v || (ov == v && oi < idx)) { v = ov; idx = oi; }
  }
  int i1 = idx;

  float a2 = (lane == i1) ? -INFINITY : a;
  v = a2;
  idx = lane;
#pragma unroll
  for (int off = 32; off > 0; off >>= 1) {
    float ov = __shfl_xor(v, off, 64);
    int oi = __shfl_xor(idx, off, 64);
    if (ov > v || (ov == v && oi < idx)) { v = ov; idx = oi; }
  }
  int i2 = idx;

  if (lane == 0) {
    idx_out[(size_t)row * 2 + 0] = (float)i1;
    idx_out[(size_t)row * 2 + 1] = (float)i2;
  }
}

// ---------------------------------------------------------------------------
extern "C" void kernel_launch(void* const* d_in, const int* in_sizes, int n_in,
                              void* d_out, int out_size, void* d_ws,
                              size_t ws_size, hipStream_t stream) {
  const float* h = (const float*)d_in[0];   // [4,4096,4096]
  const float* wr = (const float*)d_in[1];  // [4096,64]
  float* out = (float*)d_out;
  float* logits = out;                          // ROWS*EE (raw, then adjusted)
  float* idx_out = out + (size_t)ROWS * EE;     // ROWS*2
  float* g_load = (float*)d_ws;                 // 64 floats
  unsigned char* wsp = (unsigned char*)d_ws + 512;  // 1.5 MiB pre-split w

  // no memsets: g_load zeroed in k_wsplit (stream-ordered); d_out fully
  // overwritten (logits by k_gemm stores, idx by k_top2).
  k_wsplit<<<DD / KT, 256, 0, stream>>>(wr, wsp, g_load);
  k_gemm<<<ROWS / BM, 512, 0, stream>>>(h, wsp, logits, g_load);
  k_top2<<<ROWS / 4, 256, 0, stream>>>(logits, g_load, idx_out);
}

// Round 4
// 426.402 us; speedup vs baseline: 1.0543x; 1.0543x over previous
//
#include <hip/hip_runtime.h>
#include <math.h>

#define ROWS 16384
#define DD   4096
#define EE   64
#define EPSF 1e-10f

#define BM    32                 // rows per gemm block -> 512 blocks = 2/CU
#define KT    64                 // k per pipeline phase (2 x 32-k MFMA subtiles)
#define NKT   (DD / KT)          // 64 phases
#define WTILE 12288              // bytes per pre-split 32-k w tile (3*4*64*16)
#define BTILE (2 * WTILE)        // bytes per 64-k phase (24576)

typedef __attribute__((ext_vector_type(8))) short short8;   // 8 bf16
typedef __attribute__((ext_vector_type(4))) float f32x4;    // MFMA C/D
typedef __attribute__((ext_vector_type(4))) unsigned u32x4; // packed bf16x8

// RNE 3-level bf16 split of 8 floats, pair-packed into 3x (4 dwords).
__device__ __forceinline__ void split3x8(const float f[8], u32x4& w0,
                                         u32x4& w1, u32x4& w2) {
#pragma unroll
  for (int i = 0; i < 4; ++i) {
    float fa = f[2 * i], fb = f[2 * i + 1];
    unsigned ua = __float_as_uint(fa), ub = __float_as_uint(fb);
    unsigned ra = ua + 0x7fffu + ((ua >> 16) & 1u);
    unsigned rb = ub + 0x7fffu + ((ub >> 16) & 1u);
    w0[i] = (rb & 0xffff0000u) | (ra >> 16);
    fa -= __uint_as_float(ra & 0xffff0000u);
    fb -= __uint_as_float(rb & 0xffff0000u);
    ua = __float_as_uint(fa); ub = __float_as_uint(fb);
    ra = ua + 0x7fffu + ((ua >> 16) & 1u);
    rb = ub + 0x7fffu + ((ub >> 16) & 1u);
    w1[i] = (rb & 0xffff0000u) | (ra >> 16);
    fa -= __uint_as_float(ra & 0xffff0000u);
    fb -= __uint_as_float(rb & 0xffff0000u);
    ua = __float_as_uint(fa); ub = __float_as_uint(fb);
    ra = ua + 0x7fffu + ((ua >> 16) & 1u);
    rb = ub + 0x7fffu + ((ub >> 16) & 1u);
    w2[i] = (rb & 0xffff0000u) | (ra >> 16);
  }
}

__device__ __forceinline__ void dma16(const void* g, void* l) {
  __builtin_amdgcn_global_load_lds(
      (const __attribute__((address_space(1))) unsigned int*)g,
      (__attribute__((address_space(3))) unsigned int*)l, 16, 0, 0);
}

// ---------------------------------------------------------------------------
// One-time w pre-split into MFMA-B-fragment-ready layout:
//   wsp[kt32][part p][et][lp][8 bf16]; lp = k_octet*16 + (e&15), et = e>>4.
// Block 0 also zeroes g_load (stream-ordered before k_gemm's atomics).
// ---------------------------------------------------------------------------
__global__ __launch_bounds__(256) void k_wsplit(const float* __restrict__ wr,
                                                unsigned char* __restrict__ out,
                                                float* __restrict__ g_load) {
  const int kt = blockIdx.x;  // global 32-k tile 0..127
  const int t = threadIdx.x;
  const int lane = t & 63, wv = t >> 6;
  if (blockIdx.x == 0 && t < 64) g_load[t] = 0.f;
  float f[8];
  const float* wp = wr + (size_t)(kt * 32 + wv * 8) * EE + lane;
#pragma unroll
  for (int j = 0; j < 8; ++j) f[j] = wp[(size_t)j * EE];
  u32x4 w0, w1, w2;
  split3x8(f, w0, w1, w2);
  const int et = lane >> 4;
  const int lp = wv * 16 + (lane & 15);
  unsigned char* base = out + (size_t)kt * WTILE + et * 1024 + lp * 16;
  *(u32x4*)(base + 0 * 4096) = w0;
  *(u32x4*)(base + 1 * 4096) = w1;
  *(u32x4*)(base + 2 * 4096) = w2;
}

// ---------------------------------------------------------------------------
// Router GEMM + fused softmax/expert-load.
// 512 blocks (2 independent blocks/CU) x 256 thr (4 waves):
// 32 rows x 64 experts x full K=4096. Wave wv: m-tile mt=wv>>1 (16 rows),
// e-half eh=wv&1 (2 of 4 e-tiles).
// R2-proven sync structure: one vmcnt(0)+__syncthreads per phase, prefetch
// issued immediately after the barrier. Latency hidden by (a) a second
// independent block per CU and (b) fat 64-k phases (~1200 cy compute/SIMD
// vs ~900 cy HBM latency), not by hand-counted vmcnt (R3 crash lesson).
// ---------------------------------------------------------------------------
__global__ __launch_bounds__(256) void k_gemm(
    const float* __restrict__ h, const unsigned char* __restrict__ wsp,
    float* __restrict__ logits, float* __restrict__ g_load) {
  __shared__ alignas(16) unsigned char smem[2 * BTILE];  // 48 KB

  const int t = threadIdx.x;
  const int lane = t & 63;
  const int wv = t >> 6;    // 0..3
  const int mt = wv >> 1;   // m-tile 0..1
  const int eh = wv & 1;    // e-half 0..1
  const int row0 = blockIdx.x * BM;

  f32x4 acc[2] = {};

  // A: row = row0 + mt*16 + (lane&15), k = sub*32 + (lane>>4)*8 + j
  const float* ap =
      h + (size_t)(row0 + mt * 16 + (lane & 15)) * DD + (lane >> 4) * 8;
  const int dmaoff = t * 16;  // + i*4096 ; dest = wave-uniform base + lane*16

  float4 c0, c1, c2, c3, n0, n1, n2, n3;

  // prologue: phase 0 (B via 6 DMA chunks, A sub0/sub1 to regs)
#pragma unroll
  for (int i = 0; i < 6; ++i)
    dma16(wsp + i * 4096 + dmaoff, smem + i * 4096 + dmaoff);
  c0 = *(const float4*)(ap);
  c1 = *(const float4*)(ap + 4);
  c2 = *(const float4*)(ap + 32);
  c3 = *(const float4*)(ap + 36);

  for (int kt = 0; kt < NKT; ++kt) {
    const int buf = kt & 1;
    asm volatile("s_waitcnt vmcnt(0)" ::: "memory");
    __syncthreads();

    // issue next-phase prefetch NOW; full compute phase to land
    if (kt + 1 < NKT) {
      const unsigned char* ws = wsp + (size_t)(kt + 1) * BTILE;
      unsigned char* nb = smem + (buf ^ 1) * BTILE;
#pragma unroll
      for (int i = 0; i < 6; ++i)
        dma16(ws + i * 4096 + dmaoff, nb + i * 4096 + dmaoff);
      const float* p = ap + (size_t)(kt + 1) * KT;
      n0 = *(const float4*)(p);
      n1 = *(const float4*)(p + 4);
      n2 = *(const float4*)(p + 32);
      n3 = *(const float4*)(p + 36);
    }

    const unsigned char* lb = smem + buf * BTILE;
#pragma unroll
    for (int sub = 0; sub < 2; ++sub) {
      // B fragments: 3 parts x 2 e-tiles, 16B/lane linear (2-way bank = free)
      const unsigned char* sb = lb + sub * WTILE;
      short8 bf[3][2];
#pragma unroll
      for (int p = 0; p < 3; ++p)
#pragma unroll
        for (int e = 0; e < 2; ++e)
          bf[p][e] =
              *(const short8*)&sb[p * 4096 + (eh * 2 + e) * 1024 + lane * 16];

      const float4 a0 = sub ? c2 : c0;
      const float4 a1 = sub ? c3 : c1;
      const float af[8] = {a0.x, a0.y, a0.z, a0.w, a1.x, a1.y, a1.z, a1.w};
      u32x4 q0, q1, q2;
      split3x8(af, q0, q1, q2);
      const short8 ah0 = __builtin_bit_cast(short8, q0);
      const short8 ah1 = __builtin_bit_cast(short8, q1);
      const short8 ah2 = __builtin_bit_cast(short8, q2);
#pragma unroll
      for (int e = 0; e < 2; ++e) {
        f32x4 c = acc[e];
        c = __builtin_amdgcn_mfma_f32_16x16x32_bf16(ah0, bf[0][e], c, 0, 0, 0);
        c = __builtin_amdgcn_mfma_f32_16x16x32_bf16(ah0, bf[1][e], c, 0, 0, 0);
        c = __builtin_amdgcn_mfma_f32_16x16x32_bf16(ah1, bf[0][e], c, 0, 0, 0);
        c = __builtin_amdgcn_mfma_f32_16x16x32_bf16(ah0, bf[2][e], c, 0, 0, 0);
        c = __builtin_amdgcn_mfma_f32_16x16x32_bf16(ah1, bf[1][e], c, 0, 0, 0);
        c = __builtin_amdgcn_mfma_f32_16x16x32_bf16(ah2, bf[0][e], c, 0, 0, 0);
        acc[e] = c;
      }
    }

    if (kt + 1 < NKT) { c0 = n0; c1 = n1; c2 = n2; c3 = n3; }
  }

  // ---- fused epilogue: raw logits -> LDS -> softmax -> load accumulation ----
  asm volatile("s_waitcnt vmcnt(0)" ::: "memory");
  __syncthreads();                       // all waves done with smem B buffers
  float* sl = (float*)smem;              // [32][68] fp32, padded stride
  {
    const int rb = mt * 16 + (lane >> 4) * 4;     // C: row=quad*4+r
    const int cb = eh * 32 + (lane & 15);         //    col=lane&15
#pragma unroll
    for (int e = 0; e < 2; ++e)
#pragma unroll
      for (int r = 0; r < 4; ++r)
        sl[(rb + r) * 68 + cb + e * 16] = acc[e][r];
  }
  __syncthreads();

  float accp = 0.f;
#pragma unroll
  for (int i = 0; i < 8; ++i) {
    const int row = wv * 8 + i;
    const float x = sl[row * 68 + lane];
    float m = x;
#pragma unroll
    for (int off = 32; off > 0; off >>= 1) m = fmaxf(m, __shfl_xor(m, off, 64));
    const float p = __expf(x - m);
    float s = p;
#pragma unroll
    for (int off = 32; off > 0; off >>= 1) s += __shfl_xor(s, off, 64);
    accp += p / s;
    logits[(size_t)(row0 + row) * EE + lane] = x;   // raw logits, coalesced
  }
  float* red = sl + 32 * 68;             // disjoint LDS region
  red[wv * 64 + lane] = accp;
  __syncthreads();
  if (wv == 0) {
    float s = red[0 * 64 + lane] + red[1 * 64 + lane] + red[2 * 64 + lane] +
              red[3 * 64 + lane];
    atomicAdd(&g_load[lane], s);
  }
}

// ---------------------------------------------------------------------------
// penalty (recomputed per wave: 64-wide reduce + logf, trivially cheap)
// + adjusted logits + top-2. One row per wave.
// ---------------------------------------------------------------------------
__global__ __launch_bounds__(256) void k_top2(float* __restrict__ logits,
                                              const float* __restrict__ g_load,
                                              float* __restrict__ idx_out) {
  int t = threadIdx.x;
  int lane = t & 63;
  int wv = t >> 6;
  int row = blockIdx.x * 4 + wv;

  float v0 = g_load[lane];
  float s0 = v0;
#pragma unroll
  for (int off = 32; off > 0; off >>= 1) s0 += __shfl_xor(s0, off, 64);
  float lp = logf(v0 / (s0 * (1.f / 64.f) + EPSF) + EPSF);

  size_t base = (size_t)row * EE;
  float a = logits[base + lane] - lp;
  logits[base + lane] = a;

  float v = a;
  int idx = lane;
#pragma unroll
  for (int off = 32; off > 0; off >>= 1) {
    float ov = __shfl_xor(v, off, 64);
    int oi = __shfl_xor(idx, off, 64);
    if (ov > v || (ov == v && oi < idx)) { v = ov; idx = oi; }
  }
  int i1 = idx;

  float a2 = (lane == i1) ? -INFINITY : a;
  v = a2;
  idx = lane;
#pragma unroll
  for (int off = 32; off > 0; off >>= 1) {
    float ov = __shfl_xor(v, off, 64);
    int oi = __shfl_xor(idx, off, 64);
    if (ov > v || (ov == v && oi < idx)) { v = ov; idx = oi; }
  }
  int i2 = idx;

  if (lane == 0) {
    idx_out[(size_t)row * 2 + 0] = (float)i1;
    idx_out[(size_t)row * 2 + 1] = (float)i2;
  }
}

// ---------------------------------------------------------------------------
extern "C" void kernel_launch(void* const* d_in, const int* in_sizes, int n_in,
                              void* d_out, int out_size, void* d_ws,
                              size_t ws_size, hipStream_t stream) {
  const float* h = (const float*)d_in[0];   // [4,4096,4096]
  const float* wr = (const float*)d_in[1];  // [4096,64]
  float* out = (float*)d_out;
  float* logits = out;                          // ROWS*EE (raw, then adjusted)
  float* idx_out = out + (size_t)ROWS * EE;     // ROWS*2
  float* g_load = (float*)d_ws;                 // 64 floats
  unsigned char* wsp = (unsigned char*)d_ws + 512;  // 1.5 MiB pre-split w

  // no memsets: g_load zeroed in k_wsplit (stream-ordered); d_out fully
  // overwritten (logits by k_gemm stores, idx by k_top2).
  k_wsplit<<<DD / 32, 256, 0, stream>>>(wr, wsp, g_load);
  k_gemm<<<ROWS / BM, 256, 0, stream>>>(h, wsp, logits, g_load);
  k_top2<<<ROWS / 4, 256, 0, stream>>>(logits, g_load, idx_out);
}

// Round 6
// 407.987 us; speedup vs baseline: 1.1019x; 1.0451x over previous
//
#include <hip/hip_runtime.h>
#include <math.h>

#define ROWS 16384
#define DD   4096
#define EE   64
#define EPSF 1e-10f

#define BM    64                 // rows per gemm block -> 256 blocks = 1/CU
#define KT    64                 // k per pipeline phase (2 x 32-k MFMA subtiles)
#define NKT   (DD / KT)          // 64 phases
#define WTILE 12288              // bytes per pre-split 32-k w tile (3*4*64*16)
#define BTILE (2 * WTILE)        // bytes per 64-k phase (24576)

typedef __attribute__((ext_vector_type(8))) short short8;   // 8 bf16
typedef __attribute__((ext_vector_type(4))) float f32x4;    // MFMA C/D
typedef __attribute__((ext_vector_type(4))) unsigned u32x4; // packed bf16x8

// RNE 3-level bf16 split of 8 floats, pair-packed into 3x (4 dwords).
__device__ __forceinline__ void split3x8(const float f[8], u32x4& w0,
                                         u32x4& w1, u32x4& w2) {
#pragma unroll
  for (int i = 0; i < 4; ++i) {
    float fa = f[2 * i], fb = f[2 * i + 1];
    unsigned ua = __float_as_uint(fa), ub = __float_as_uint(fb);
    unsigned ra = ua + 0x7fffu + ((ua >> 16) & 1u);
    unsigned rb = ub + 0x7fffu + ((ub >> 16) & 1u);
    w0[i] = (rb & 0xffff0000u) | (ra >> 16);
    fa -= __uint_as_float(ra & 0xffff0000u);
    fb -= __uint_as_float(rb & 0xffff0000u);
    ua = __float_as_uint(fa); ub = __float_as_uint(fb);
    ra = ua + 0x7fffu + ((ua >> 16) & 1u);
    rb = ub + 0x7fffu + ((ub >> 16) & 1u);
    w1[i] = (rb & 0xffff0000u) | (ra >> 16);
    fa -= __uint_as_float(ra & 0xffff0000u);
    fb -= __uint_as_float(rb & 0xffff0000u);
    ua = __float_as_uint(fa); ub = __float_as_uint(fb);
    ra = ua + 0x7fffu + ((ua >> 16) & 1u);
    rb = ub + 0x7fffu + ((ub >> 16) & 1u);
    w2[i] = (rb & 0xffff0000u) | (ra >> 16);
  }
}

__device__ __forceinline__ void dma16(const void* g, void* l) {
  __builtin_amdgcn_global_load_lds(
      (const __attribute__((address_space(1))) unsigned int*)g,
      (__attribute__((address_space(3))) unsigned int*)l, 16, 0, 0);
}

// ---------------------------------------------------------------------------
// One-time w pre-split into MFMA-B-fragment-ready layout:
//   wsp[kt32][part p][et][lp][8 bf16]; lp = k_octet*16 + (e&15), et = e>>4.
// Block 0 also zeroes g_load (stream-ordered before k_gemm's atomics).
// ---------------------------------------------------------------------------
__global__ __launch_bounds__(256) void k_wsplit(const float* __restrict__ wr,
                                                unsigned char* __restrict__ out,
                                                float* __restrict__ g_load) {
  const int kt = blockIdx.x;  // global 32-k tile 0..127
  const int t = threadIdx.x;
  const int lane = t & 63, wv = t >> 6;
  if (blockIdx.x == 0 && t < 64) g_load[t] = 0.f;
  float f[8];
  const float* wp = wr + (size_t)(kt * 32 + wv * 8) * EE + lane;
#pragma unroll
  for (int j = 0; j < 8; ++j) f[j] = wp[(size_t)j * EE];
  u32x4 w0, w1, w2;
  split3x8(f, w0, w1, w2);
  const int et = lane >> 4;
  const int lp = wv * 16 + (lane & 15);
  unsigned char* base = out + (size_t)kt * WTILE + et * 1024 + lp * 16;
  *(u32x4*)(base + 0 * 4096) = w0;
  *(u32x4*)(base + 1 * 4096) = w1;
  *(u32x4*)(base + 2 * 4096) = w2;
}

// ---------------------------------------------------------------------------
// Router GEMM + fused softmax/expert-load.
// 256 blocks (1/CU) x 512 thr (8 waves): 64 rows x 64 experts x full K=4096.
// Wave wv: m-tile mt=wv>>1 (16 rows), k-subtile sub=wv&1 (32 of 64 k/phase),
// ALL 4 e-tiles per wave -> each A fragment split exactly ONCE (no e-half
// duplication of split3x8), A loads non-duplicated, B re-reads halved
// (256 blocks, not 512). The two k-subtile partial accs are summed in the
// LDS epilogue. R4-proven sync skeleton: one vmcnt(0)+__syncthreads per
// phase, prefetch issued immediately after the barrier.
// ---------------------------------------------------------------------------
__global__ __launch_bounds__(512) void k_gemm(
    const float* __restrict__ h, const unsigned char* __restrict__ wsp,
    float* __restrict__ logits, float* __restrict__ g_load) {
  __shared__ alignas(16) unsigned char smem[2 * BTILE];  // 48 KB

  const int t = threadIdx.x;
  const int lane = t & 63;
  const int wv = t >> 6;    // 0..7
  const int mt = wv >> 1;   // m-tile 0..3 (16 rows each)
  const int sub = wv & 1;   // k-subtile 0..1 (32 k each)
  const int row0 = blockIdx.x * BM;

  f32x4 acc[4] = {};        // 4 e-tiles, partial over this wave's k-subtiles

  // A: row = row0 + mt*16 + (lane&15), k = kt*64 + sub*32 + (lane>>4)*8 + j
  const float* ap = h + (size_t)(row0 + mt * 16 + (lane & 15)) * DD +
                    sub * 32 + (lane >> 4) * 8;
  // B DMA: 3 chunks of 8 KB per phase; dest = wave-uniform base + lane*16
  const int dmaoff = t * 16;  // + i*8192

  float4 c0, c1, n0, n1;

  // prologue: phase 0 (B 24 KB via 3 DMA chunks, A 8 floats to regs)
#pragma unroll
  for (int i = 0; i < 3; ++i)
    dma16(wsp + i * 8192 + dmaoff, smem + i * 8192 + dmaoff);
  c0 = *(const float4*)(ap);
  c1 = *(const float4*)(ap + 4);

  for (int kt = 0; kt < NKT; ++kt) {
    const int buf = kt & 1;
    asm volatile("s_waitcnt vmcnt(0)" ::: "memory");
    __syncthreads();

    // issue next-phase prefetch NOW; full compute phase to land
    if (kt + 1 < NKT) {
      const unsigned char* ws = wsp + (size_t)(kt + 1) * BTILE;
      unsigned char* nb = smem + (buf ^ 1) * BTILE;
#pragma unroll
      for (int i = 0; i < 3; ++i)
        dma16(ws + i * 8192 + dmaoff, nb + i * 8192 + dmaoff);
      const float* p = ap + (size_t)(kt + 1) * KT;
      n0 = *(const float4*)(p);
      n1 = *(const float4*)(p + 4);
    }

    // B fragments for this wave's k-subtile: 3 parts x 4 e-tiles
    const unsigned char* lb = smem + buf * BTILE + sub * WTILE;
    short8 bf[3][4];
#pragma unroll
    for (int p = 0; p < 3; ++p)
#pragma unroll
      for (int e = 0; e < 4; ++e)
        bf[p][e] = *(const short8*)&lb[p * 4096 + e * 1024 + lane * 16];

    // split this wave's A fragment ONCE
    const float af[8] = {c0.x, c0.y, c0.z, c0.w, c1.x, c1.y, c1.z, c1.w};
    u32x4 q0, q1, q2;
    split3x8(af, q0, q1, q2);
    const short8 ah0 = __builtin_bit_cast(short8, q0);
    const short8 ah1 = __builtin_bit_cast(short8, q1);
    const short8 ah2 = __builtin_bit_cast(short8, q2);
#pragma unroll
    for (int e = 0; e < 4; ++e) {
      f32x4 c = acc[e];
      c = __builtin_amdgcn_mfma_f32_16x16x32_bf16(ah0, bf[0][e], c, 0, 0, 0);
      c = __builtin_amdgcn_mfma_f32_16x16x32_bf16(ah0, bf[1][e], c, 0, 0, 0);
      c = __builtin_amdgcn_mfma_f32_16x16x32_bf16(ah1, bf[0][e], c, 0, 0, 0);
      c = __builtin_amdgcn_mfma_f32_16x16x32_bf16(ah0, bf[2][e], c, 0, 0, 0);
      c = __builtin_amdgcn_mfma_f32_16x16x32_bf16(ah1, bf[1][e], c, 0, 0, 0);
      c = __builtin_amdgcn_mfma_f32_16x16x32_bf16(ah2, bf[0][e], c, 0, 0, 0);
      acc[e] = c;
    }

    if (kt + 1 < NKT) { c0 = n0; c1 = n1; }
  }

  // ---- fused epilogue: pair-wave k-sum -> softmax -> load accumulation ----
  asm volatile("s_waitcnt vmcnt(0)" ::: "memory");
  __syncthreads();                       // all waves done with smem B buffers
  float* sl = (float*)smem;              // [64][68] fp32, padded stride
  {
    const int rb = mt * 16 + (lane >> 4) * 4;     // C: row=quad*4+r
    const int cb = lane & 15;                     //    col=lane&15
    if (sub == 0) {
#pragma unroll
      for (int e = 0; e < 4; ++e)
#pragma unroll
        for (int r = 0; r < 4; ++r)
          sl[(rb + r) * 68 + e * 16 + cb] = acc[e][r];
    }
    __syncthreads();
    if (sub == 1) {
#pragma unroll
      for (int e = 0; e < 4; ++e)
#pragma unroll
        for (int r = 0; r < 4; ++r)
          sl[(rb + r) * 68 + e * 16 + cb] += acc[e][r];
    }
    __syncthreads();
  }

  float accp = 0.f;
#pragma unroll
  for (int i = 0; i < 8; ++i) {
    const int row = wv * 8 + i;
    const float x = sl[row * 68 + lane];
    float m = x;
#pragma unroll
    for (int off = 32; off > 0; off >>= 1) m = fmaxf(m, __shfl_xor(m, off, 64));
    const float p = __expf(x - m);
    float s = p;
#pragma unroll
    for (int off = 32; off > 0; off >>= 1) s += __shfl_xor(s, off, 64);
    accp += p / s;
    logits[(size_t)(row0 + row) * EE + lane] = x;   // raw logits, coalesced
  }
  float* red = sl + 64 * 68;             // disjoint LDS region
  red[wv * 64 + lane] = accp;
  __syncthreads();
  if (wv == 0) {
    float s = 0.f;
#pragma unroll
    for (int j = 0; j < 8; ++j) s += red[j * 64 + lane];
    atomicAdd(&g_load[lane], s);
  }
}

// ---------------------------------------------------------------------------
// penalty (recomputed per wave: 64-wide reduce + logf, trivially cheap)
// + adjusted logits + top-2. One row per wave.
// ---------------------------------------------------------------------------
__global__ __launch_bounds__(256) void k_top2(float* __restrict__ logits,
                                              const float* __restrict__ g_load,
                                              float* __restrict__ idx_out) {
  int t = threadIdx.x;
  int lane = t & 63;
  int wv = t >> 6;
  int row = blockIdx.x * 4 + wv;

  float v0 = g_load[lane];
  float s0 = v0;
#pragma unroll
  for (int off = 32; off > 0; off >>= 1) s0 += __shfl_xor(s0, off, 64);
  float lp = logf(v0 / (s0 * (1.f / 64.f) + EPSF) + EPSF);

  size_t base = (size_t)row * EE;
  float a = logits[base + lane] - lp;
  logits[base + lane] = a;

  float v = a;
  int idx = lane;
#pragma unroll
  for (int off = 32; off > 0; off >>= 1) {
    float ov = __shfl_xor(v, off, 64);
    int oi = __shfl_xor(idx, off, 64);
    if (ov > v || (ov == v && oi < idx)) { v = ov; idx = oi; }
  }
  int i1 = idx;

  float a2 = (lane == i1) ? -INFINITY : a;
  v = a2;
  idx = lane;
#pragma unroll
  for (int off = 32; off > 0; off >>= 1) {
    float ov = __shfl_xor(v, off, 64);
    int oi = __shfl_xor(idx, off, 64);
    if (ov > v || (ov == v && oi < idx)) { v = ov; idx = oi; }
  }
  int i2 = idx;

  if (lane == 0) {
    idx_out[(size_t)row * 2 + 0] = (float)i1;
    idx_out[(size_t)row * 2 + 1] = (float)i2;
  }
}

// ---------------------------------------------------------------------------
extern "C" void kernel_launch(void* const* d_in, const int* in_sizes, int n_in,
                              void* d_out, int out_size, void* d_ws,
                              size_t ws_size, hipStream_t stream) {
  const float* h = (const float*)d_in[0];   // [4,4096,4096]
  const float* wr = (const float*)d_in[1];  // [4096,64]
  float* out = (float*)d_out;
  float* logits = out;                          // ROWS*EE (raw, then adjusted)
  float* idx_out = out + (size_t)ROWS * EE;     // ROWS*2
  float* g_load = (float*)d_ws;                 // 64 floats
  unsigned char* wsp = (unsigned char*)d_ws + 512;  // 1.5 MiB pre-split w

  // no memsets: g_load zeroed in k_wsplit (stream-ordered); d_out fully
  // overwritten (logits by k_gemm stores, idx by k_top2).
  k_wsplit<<<DD / 32, 256, 0, stream>>>(wr, wsp, g_load);
  k_gemm<<<ROWS / BM, 512, 0, stream>>>(h, wsp, logits, g_load);
  k_top2<<<ROWS / 4, 256, 0, stream>>>(logits, g_load, idx_out);
}

// Round 7
// 399.164 us; speedup vs baseline: 1.1262x; 1.0221x over previous
//
#include <hip/hip_runtime.h>
#include <math.h>

#define ROWS 16384
#define DD   4096
#define EE   64
#define EPSF 1e-10f

#define BM    64                 // rows per gemm block -> 256 blocks = 1/CU
#define KT    64                 // k per pipeline phase (2 x 32-k MFMA subtiles)
#define NKT   (DD / KT)          // 64 phases
#define WTILE 8192               // bytes per pre-split 32-k w tile (2*4*64*16)
#define BTILE (2 * WTILE)        // bytes per 64-k phase (16384)

typedef __attribute__((ext_vector_type(8))) short short8;   // 8 bf16
typedef __attribute__((ext_vector_type(4))) float f32x4;    // MFMA C/D
typedef __attribute__((ext_vector_type(4))) unsigned u32x4; // packed bf16x8

// RNE 2-level bf16 split of 8 floats, pair-packed into 2x (4 dwords).
// a ~= a0 + a1 with |a - a0 - a1| <= 2^-18 |a|.
__device__ __forceinline__ void split2x8(const float f[8], u32x4& w0,
                                         u32x4& w1) {
#pragma unroll
  for (int i = 0; i < 4; ++i) {
    float fa = f[2 * i], fb = f[2 * i + 1];
    unsigned ua = __float_as_uint(fa), ub = __float_as_uint(fb);
    unsigned ra = ua + 0x7fffu + ((ua >> 16) & 1u);
    unsigned rb = ub + 0x7fffu + ((ub >> 16) & 1u);
    w0[i] = (rb & 0xffff0000u) | (ra >> 16);
    fa -= __uint_as_float(ra & 0xffff0000u);
    fb -= __uint_as_float(rb & 0xffff0000u);
    ua = __float_as_uint(fa); ub = __float_as_uint(fb);
    ra = ua + 0x7fffu + ((ua >> 16) & 1u);
    rb = ub + 0x7fffu + ((ub >> 16) & 1u);
    w1[i] = (rb & 0xffff0000u) | (ra >> 16);
  }
}

__device__ __forceinline__ void dma16(const void* g, void* l) {
  __builtin_amdgcn_global_load_lds(
      (const __attribute__((address_space(1))) unsigned int*)g,
      (__attribute__((address_space(3))) unsigned int*)l, 16, 0, 0);
}

// ---------------------------------------------------------------------------
// One-time w pre-split (2-part) into MFMA-B-fragment-ready layout:
//   wsp[kt32][part p(2)][et(4)][lp(64)][8 bf16]; lp = k_octet*16 + (e&15).
// Block 0 also zeroes g_load (stream-ordered before k_gemm's atomics).
// ---------------------------------------------------------------------------
__global__ __launch_bounds__(256) void k_wsplit(const float* __restrict__ wr,
                                                unsigned char* __restrict__ out,
                                                float* __restrict__ g_load) {
  const int kt = blockIdx.x;  // global 32-k tile 0..127
  const int t = threadIdx.x;
  const int lane = t & 63, wv = t >> 6;
  if (blockIdx.x == 0 && t < 64) g_load[t] = 0.f;
  float f[8];
  const float* wp = wr + (size_t)(kt * 32 + wv * 8) * EE + lane;
#pragma unroll
  for (int j = 0; j < 8; ++j) f[j] = wp[(size_t)j * EE];
  u32x4 w0, w1;
  split2x8(f, w0, w1);
  const int et = lane >> 4;
  const int lp = wv * 16 + (lane & 15);
  unsigned char* base = out + (size_t)kt * WTILE + et * 1024 + lp * 16;
  *(u32x4*)(base + 0 * 4096) = w0;
  *(u32x4*)(base + 1 * 4096) = w1;
}

// ---------------------------------------------------------------------------
// Router GEMM + fused softmax/expert-load.
// 256 blocks (1/CU) x 512 thr (8 waves): 64 rows x 64 experts x full K=4096.
// Wave wv: m-tile mt=wv>>1 (16 rows), k-subtile sub=wv&1 (32 of 64 k/phase),
// all 4 e-tiles per wave. 3-term split-product GEMM (a0b0+a0b1+a1b0):
// error ~2^-17 per product, logit-level ~1e-5 -- far below the 0.0156
// comparison scale. B pre-split 2-part (1 MiB): per-CU VMEM traffic
// = A 1 MB + B 1 MB = 2 MB -> ~83 us at the ~10 B/cyc/CU streaming cap.
// R6-proven sync skeleton: one vmcnt(0)+__syncthreads per phase, prefetch
// issued immediately after the barrier; pair-wave k-sum in LDS epilogue.
// ---------------------------------------------------------------------------
__global__ __launch_bounds__(512) void k_gemm(
    const float* __restrict__ h, const unsigned char* __restrict__ wsp,
    float* __restrict__ logits, float* __restrict__ g_load) {
  __shared__ alignas(16) unsigned char smem[2 * BTILE];  // 32 KB

  const int t = threadIdx.x;
  const int lane = t & 63;
  const int wv = t >> 6;    // 0..7
  const int mt = wv >> 1;   // m-tile 0..3 (16 rows each)
  const int sub = wv & 1;   // k-subtile 0..1 (32 k each)
  const int row0 = blockIdx.x * BM;

  f32x4 acc[4] = {};        // 4 e-tiles, partial over this wave's k-subtiles

  // A: row = row0 + mt*16 + (lane&15), k = kt*64 + sub*32 + (lane>>4)*8 + j
  const float* ap = h + (size_t)(row0 + mt * 16 + (lane & 15)) * DD +
                    sub * 32 + (lane >> 4) * 8;
  // B DMA: 2 chunks of 8 KB per phase; dest = wave-uniform base + lane*16
  const int dmaoff = t * 16;  // + i*8192

  float4 c0, c1, n0, n1;

  // prologue: phase 0 (B 16 KB via 2 DMA chunks, A 8 floats to regs)
#pragma unroll
  for (int i = 0; i < 2; ++i)
    dma16(wsp + i * 8192 + dmaoff, smem + i * 8192 + dmaoff);
  c0 = *(const float4*)(ap);
  c1 = *(const float4*)(ap + 4);

  for (int kt = 0; kt < NKT; ++kt) {
    const int buf = kt & 1;
    asm volatile("s_waitcnt vmcnt(0)" ::: "memory");
    __syncthreads();

    // issue next-phase prefetch NOW; full compute phase to land
    if (kt + 1 < NKT) {
      const unsigned char* ws = wsp + (size_t)(kt + 1) * BTILE;
      unsigned char* nb = smem + (buf ^ 1) * BTILE;
#pragma unroll
      for (int i = 0; i < 2; ++i)
        dma16(ws + i * 8192 + dmaoff, nb + i * 8192 + dmaoff);
      const float* p = ap + (size_t)(kt + 1) * KT;
      n0 = *(const float4*)(p);
      n1 = *(const float4*)(p + 4);
    }

    // B fragments for this wave's k-subtile: 2 parts x 4 e-tiles
    const unsigned char* lb = smem + buf * BTILE + sub * WTILE;
    short8 bf[2][4];
#pragma unroll
    for (int p = 0; p < 2; ++p)
#pragma unroll
      for (int e = 0; e < 4; ++e)
        bf[p][e] = *(const short8*)&lb[p * 4096 + e * 1024 + lane * 16];

    // split this wave's A fragment ONCE (2-part)
    const float af[8] = {c0.x, c0.y, c0.z, c0.w, c1.x, c1.y, c1.z, c1.w};
    u32x4 q0, q1;
    split2x8(af, q0, q1);
    const short8 ah0 = __builtin_bit_cast(short8, q0);
    const short8 ah1 = __builtin_bit_cast(short8, q1);
#pragma unroll
    for (int e = 0; e < 4; ++e) {
      f32x4 c = acc[e];
      c = __builtin_amdgcn_mfma_f32_16x16x32_bf16(ah0, bf[0][e], c, 0, 0, 0);
      c = __builtin_amdgcn_mfma_f32_16x16x32_bf16(ah0, bf[1][e], c, 0, 0, 0);
      c = __builtin_amdgcn_mfma_f32_16x16x32_bf16(ah1, bf[0][e], c, 0, 0, 0);
      acc[e] = c;
    }

    if (kt + 1 < NKT) { c0 = n0; c1 = n1; }
  }

  // ---- fused epilogue: pair-wave k-sum -> softmax -> load accumulation ----
  asm volatile("s_waitcnt vmcnt(0)" ::: "memory");
  __syncthreads();                       // all waves done with smem B buffers
  float* sl = (float*)smem;              // [64][68] fp32, padded stride
  {
    const int rb = mt * 16 + (lane >> 4) * 4;     // C: row=quad*4+r
    const int cb = lane & 15;                     //    col=lane&15
    if (sub == 0) {
#pragma unroll
      for (int e = 0; e < 4; ++e)
#pragma unroll
        for (int r = 0; r < 4; ++r)
          sl[(rb + r) * 68 + e * 16 + cb] = acc[e][r];
    }
    __syncthreads();
    if (sub == 1) {
#pragma unroll
      for (int e = 0; e < 4; ++e)
#pragma unroll
        for (int r = 0; r < 4; ++r)
          sl[(rb + r) * 68 + e * 16 + cb] += acc[e][r];
    }
    __syncthreads();
  }

  float accp = 0.f;
#pragma unroll
  for (int i = 0; i < 8; ++i) {
    const int row = wv * 8 + i;
    const float x = sl[row * 68 + lane];
    float m = x;
#pragma unroll
    for (int off = 32; off > 0; off >>= 1) m = fmaxf(m, __shfl_xor(m, off, 64));
    const float p = __expf(x - m);
    float s = p;
#pragma unroll
    for (int off = 32; off > 0; off >>= 1) s += __shfl_xor(s, off, 64);
    accp += p / s;
    logits[(size_t)(row0 + row) * EE + lane] = x;   // raw logits, coalesced
  }
  float* red = sl + 64 * 68;             // disjoint LDS region (fits: 19456B)
  red[wv * 64 + lane] = accp;
  __syncthreads();
  if (wv == 0) {
    float s = 0.f;
#pragma unroll
    for (int j = 0; j < 8; ++j) s += red[j * 64 + lane];
    atomicAdd(&g_load[lane], s);
  }
}

// ---------------------------------------------------------------------------
// penalty (recomputed per wave: 64-wide reduce + logf, trivially cheap)
// + adjusted logits + top-2. One row per wave.
// ---------------------------------------------------------------------------
__global__ __launch_bounds__(256) void k_top2(float* __restrict__ logits,
                                              const float* __restrict__ g_load,
                                              float* __restrict__ idx_out) {
  int t = threadIdx.x;
  int lane = t & 63;
  int wv = t >> 6;
  int row = blockIdx.x * 4 + wv;

  float v0 = g_load[lane];
  float s0 = v0;
#pragma unroll
  for (int off = 32; off > 0; off >>= 1) s0 += __shfl_xor(s0, off, 64);
  float lp = logf(v0 / (s0 * (1.f / 64.f) + EPSF) + EPSF);

  size_t base = (size_t)row * EE;
  float a = logits[base + lane] - lp;
  logits[base + lane] = a;

  float v = a;
  int idx = lane;
#pragma unroll
  for (int off = 32; off > 0; off >>= 1) {
    float ov = __shfl_xor(v, off, 64);
    int oi = __shfl_xor(idx, off, 64);
    if (ov > v || (ov == v && oi < idx)) { v = ov; idx = oi; }
  }
  int i1 = idx;

  float a2 = (lane == i1) ? -INFINITY : a;
  v = a2;
  idx = lane;
#pragma unroll
  for (int off = 32; off > 0; off >>= 1) {
    float ov = __shfl_xor(v, off, 64);
    int oi = __shfl_xor(idx, off, 64);
    if (ov > v || (ov == v && oi < idx)) { v = ov; idx = oi; }
  }
  int i2 = idx;

  if (lane == 0) {
    idx_out[(size_t)row * 2 + 0] = (float)i1;
    idx_out[(size_t)row * 2 + 1] = (float)i2;
  }
}

// ---------------------------------------------------------------------------
extern "C" void kernel_launch(void* const* d_in, const int* in_sizes, int n_in,
                              void* d_out, int out_size, void* d_ws,
                              size_t ws_size, hipStream_t stream) {
  const float* h = (const float*)d_in[0];   // [4,4096,4096]
  const float* wr = (const float*)d_in[1];  // [4096,64]
  float* out = (float*)d_out;
  float* logits = out;                          // ROWS*EE (raw, then adjusted)
  float* idx_out = out + (size_t)ROWS * EE;     // ROWS*2
  float* g_load = (float*)d_ws;                 // 64 floats
  unsigned char* wsp = (unsigned char*)d_ws + 512;  // 1 MiB pre-split w

  // no memsets: g_load zeroed in k_wsplit (stream-ordered); d_out fully
  // overwritten (logits by k_gemm stores, idx by k_top2).
  k_wsplit<<<DD / 32, 256, 0, stream>>>(wr, wsp, g_load);
  k_gemm<<<ROWS / BM, 512, 0, stream>>>(h, wsp, logits, g_load);
  k_top2<<<ROWS / 4, 256, 0, stream>>>(logits, g_load, idx_out);
}